// Round 4
// baseline (84.264 us; speedup 1.0000x reference)
//
#include <hip/hip_runtime.h>

// TimeNormalization: EMA scan over time + normalization.
//   s_t = 0.1*[x, x^2] + 0.9*s_{t-1}   (per (b,f), scan over t)
//   x_norm = (x - m) / sqrt(v - m^2 + 1e-3)
// Outputs concatenated: x_norm [B,T,F] then final_state [2,B,F].
//
// Chunked scan with halo warmup (0.9^128 ~ 1.4e-6). Evidence synthesis
// R1-R3: need vec4 (1 KB/wave-instr) AND >=2 waves/SIMD simultaneously;
// each alone is neutral at ~2.7 TB/s. This round: CL=64 (NCHUNK=64,
// 1024 blocks x 128 thr = 8 waves/CU) + vec4 + unroll 16. Chunks whose
// halo reaches t=0 start from the exact init state (no truncation).

namespace {
constexpr int Bc = 16, Tc = 4096, Fc = 512;
constexpr int CL = 64;           // chunk length
constexpr int KH = 128;          // halo (accuracy-critical, don't shrink)
constexpr int NCHUNK = Tc / CL;  // 64
constexpr int F4 = Fc / 4;       // 128 float4 columns
constexpr float ALPHA = 0.1f;
constexpr float OMA = 0.9f;
constexpr float EPS = 1e-3f;
typedef float v4 __attribute__((ext_vector_type(4)));
}

__global__ __launch_bounds__(128) void tn_kernel(const v4* __restrict__ x4,
                                                 const v4* __restrict__ st4,
                                                 v4* __restrict__ out4) {
    const int chunk = blockIdx.x & (NCHUNK - 1);
    const int b = blockIdx.x >> 6;         // NCHUNK = 64
    const int f4 = threadIdx.x;            // 0..127, coalesced float4 columns
    const int t0 = chunk * CL;

    // halo start, clamped at 0; if clamped, init from the exact given state
    int h0 = t0 - KH;
    if (h0 < 0) h0 = 0;

    v4 s_m, s_v;
    if (h0 == 0) {
        // exact initial state: state[0,b,:] (mean), state[1,b,:] (mean-square)
        s_m = st4[(size_t)b * F4 + f4];
        s_v = st4[(size_t)(Bc + b) * F4 + f4];
    } else {
        s_m = (v4)0.f;
        s_v = (v4)0.f;
    }

    const int hl = t0 - h0;                // 0, 64, or 128
    const v4* wp = x4 + ((size_t)b * Tc + h0) * F4 + f4;
#pragma unroll 16
    for (int i = 0; i < hl; ++i) {
        v4 xv = wp[(size_t)i * F4];
        v4 px = ALPHA * xv;
        s_m = OMA * s_m + px;              // 4 independent fma chains
        s_v = OMA * s_v + px * xv;
    }

    const size_t base = ((size_t)b * Tc + t0) * F4 + f4;
    const v4* xp = x4 + base;
    v4* op = out4 + base;
#pragma unroll 16
    for (int i = 0; i < CL; ++i) {
        v4 xv = xp[(size_t)i * F4];
        v4 px = ALPHA * xv;
        s_m = OMA * s_m + px;
        s_v = OMA * s_v + px * xv;
        v4 var = s_v - s_m * s_m + (v4)EPS;
        v4 r;
#pragma unroll
        for (int c = 0; c < 4; ++c) r[c] = (xv[c] - s_m[c]) * rsqrtf(var[c]);
        __builtin_nontemporal_store(r, &op[(size_t)i * F4]);  // write-once stream
    }

    if (chunk == NCHUNK - 1) {
        // final_state [2,B,F] appended after x_norm
        const size_t so = (size_t)Bc * Tc * F4;
        out4[so + (size_t)b * F4 + f4] = s_m;
        out4[so + (size_t)(Bc + b) * F4 + f4] = s_v;
    }
}

extern "C" void kernel_launch(void* const* d_in, const int* in_sizes, int n_in,
                              void* d_out, int out_size, void* d_ws, size_t ws_size,
                              hipStream_t stream) {
    const v4* x = (const v4*)d_in[0];       // [B,T,F] f32
    const v4* st = (const v4*)d_in[1];      // [2,B,F] f32
    v4* out = (v4*)d_out;                   // x_norm + final_state

    dim3 grid(Bc * NCHUNK);                 // 1024
    dim3 block(128);                        // F/4 lanes
    tn_kernel<<<grid, block, 0, stream>>>(x, st, out);
}

// Round 5
// 67.288 us; speedup vs baseline: 1.2523x; 1.2523x over previous
//
#include <hip/hip_runtime.h>

// TimeNormalization: EMA scan over time + normalization.
//   s_t = 0.1*[x, x^2] + 0.9*s_{t-1}   (per (b,f), scan over t)
//   x_norm = (x - m) / sqrt(v - m^2 + 1e-3)
// Outputs concatenated: x_norm [B,T,F] then final_state [2,B,F].
//
// Chunked scan with KH=128 halo warmup (0.9^128 ~ 1.4e-6; chunk 0 exact).
// R1-R4 evidence: BW pinned at ~2.7 TB/s in ALL configs (scalar/vec4,
// 4-16 waves/CU) -> theory: per-iteration load->wait->store interleave
// couples every load-wait to a full store drain (vmcnt retires in order).
// Fix: explicit register double-buffer pipeline — next batch's loads are
// issued ABOVE this batch's compute+stores (sched_barrier-pinned), so
// load-waits never drain stores.

namespace {
constexpr int Bc = 16, Tc = 4096, Fc = 512;
constexpr int CL = 128;          // chunk length (lowest-traffic geometry)
constexpr int KH = 128;          // halo (accuracy-critical, don't shrink)
constexpr int NCHUNK = Tc / CL;  // 32
constexpr int F4 = Fc / 4;       // 128 float4 columns
constexpr int U = 8;             // main-loop pipeline depth
constexpr int UH = 16;           // halo pipeline depth
constexpr float ALPHA = 0.1f;
constexpr float OMA = 0.9f;
constexpr float EPS = 1e-3f;
typedef float v4 __attribute__((ext_vector_type(4)));
}

__global__ __launch_bounds__(128, 2) void tn_kernel(const v4* __restrict__ x4,
                                                    const v4* __restrict__ st4,
                                                    v4* __restrict__ out4) {
    const int chunk = blockIdx.x & (NCHUNK - 1);
    const int b = blockIdx.x >> 5;         // NCHUNK = 32
    const int f4 = threadIdx.x;            // 0..127, coalesced float4 columns
    const int t0 = chunk * CL;

    v4 s_m, s_v;
    if (chunk == 0) {
        // exact initial state: state[0,b,:] (mean), state[1,b,:] (mean-square)
        s_m = st4[(size_t)b * F4 + f4];
        s_v = st4[(size_t)(Bc + b) * F4 + f4];
    } else {
        // halo warmup from t0-KH; loads-only loop, deep register prefetch
        s_m = (v4)0.f;
        s_v = (v4)0.f;
        const v4* wp = x4 + ((size_t)b * Tc + (t0 - KH)) * F4 + f4;
        v4 hb[UH];
#pragma unroll
        for (int j = 0; j < UH; ++j) hb[j] = wp[(size_t)j * F4];
        for (int i = 0; i < KH; i += UH) {
            v4 nb[UH];
            if (i + UH < KH) {
#pragma unroll
                for (int j = 0; j < UH; ++j) nb[j] = wp[(size_t)(i + UH + j) * F4];
            }
            __builtin_amdgcn_sched_barrier(0);  // keep prefetch above compute
#pragma unroll
            for (int j = 0; j < UH; ++j) {
                v4 xv = hb[j];
                v4 px = ALPHA * xv;
                s_m = OMA * s_m + px;          // 4 independent fma chains
                s_v = OMA * s_v + px * xv;
            }
#pragma unroll
            for (int j = 0; j < UH; ++j) hb[j] = nb[j];
        }
    }

    const size_t base = ((size_t)b * Tc + t0) * F4 + f4;
    const v4* xp = x4 + base;
    v4* op = out4 + base;

    // software-pipelined main loop: batch k+1 loads issue BEFORE batch k
    // stores, so consuming them never waits on store retirement (vmcnt FIFO).
    v4 buf[U];
#pragma unroll
    for (int j = 0; j < U; ++j) buf[j] = xp[(size_t)j * F4];
    for (int i = 0; i < CL; i += U) {
        v4 nbuf[U];
        if (i + U < CL) {
#pragma unroll
            for (int j = 0; j < U; ++j) nbuf[j] = xp[(size_t)(i + U + j) * F4];
        }
        __builtin_amdgcn_sched_barrier(0);      // pin loads above stores
#pragma unroll
        for (int j = 0; j < U; ++j) {
            v4 xv = buf[j];
            v4 px = ALPHA * xv;
            s_m = OMA * s_m + px;
            s_v = OMA * s_v + px * xv;
            v4 var = s_v - s_m * s_m + (v4)EPS;
            v4 r;
#pragma unroll
            for (int c = 0; c < 4; ++c) r[c] = (xv[c] - s_m[c]) * rsqrtf(var[c]);
            __builtin_nontemporal_store(r, &op[(size_t)(i + j) * F4]);
        }
#pragma unroll
        for (int j = 0; j < U; ++j) buf[j] = nbuf[j];
    }

    if (chunk == NCHUNK - 1) {
        // final_state [2,B,F] appended after x_norm
        const size_t so = (size_t)Bc * Tc * F4;
        out4[so + (size_t)b * F4 + f4] = s_m;
        out4[so + (size_t)(Bc + b) * F4 + f4] = s_v;
    }
}

extern "C" void kernel_launch(void* const* d_in, const int* in_sizes, int n_in,
                              void* d_out, int out_size, void* d_ws, size_t ws_size,
                              hipStream_t stream) {
    const v4* x = (const v4*)d_in[0];       // [B,T,F] f32
    const v4* st = (const v4*)d_in[1];      // [2,B,F] f32
    v4* out = (v4*)d_out;                   // x_norm + final_state

    dim3 grid(Bc * NCHUNK);                 // 512
    dim3 block(128);                        // F/4 lanes
    tn_kernel<<<grid, block, 0, stream>>>(x, st, out);
}

// Round 6
// 49.472 us; speedup vs baseline: 1.7033x; 1.3601x over previous
//
#include <hip/hip_runtime.h>

// TimeNormalization: EMA scan over time + normalization.
//   s_t = 0.1*[x, x^2] + 0.9*s_{t-1}   (per (b,f), scan over t)
//   x_norm = (x - m) / sqrt(v - m^2 + 1e-3)
// Outputs concatenated: x_norm [B,T,F] then final_state [2,B,F].
//
// R1-R5 synthesis: total L2-miss traffic / bench time = 5.9-6.3 TB/s in
// EVERY config (scalar/vec4, 4-16 waves/CU, pipelined or not) — the same
// ceiling as the float4 copy ubench. L3 hits cost fabric like HBM does.
// => we are at the fabric roofline; the only lever is BYTES.
// bytes = 134*(1 + KH/CL) + 131 MB. This round: CL=512 (amp 1.25),
// scalar loads, 1024 waves (4/CU — R3 proved this saturates the fabric).
// KH=128 stays (0.9^128 ~ 1.4e-6; accuracy-pinned).

namespace {
constexpr int Bc = 16, Tc = 4096, Fc = 512;
constexpr int CL = 512;          // chunk length (amp = 1 + 128/512 = 1.25)
constexpr int KH = 128;          // halo (accuracy-critical, don't shrink)
constexpr int NCHUNK = Tc / CL;  // 8
constexpr float ALPHA = 0.1f;
constexpr float OMA = 0.9f;
constexpr float EPS = 1e-3f;
}

__global__ __launch_bounds__(256) void tn_kernel(const float* __restrict__ x,
                                                 const float* __restrict__ state,
                                                 float* __restrict__ out) {
    // grid = B * NCHUNK * 2 = 256 blocks (1 per CU), 256 threads each
    const int bid = blockIdx.x;
    const int fh = bid & 1;                // which half of F
    const int chunk = (bid >> 1) & (NCHUNK - 1);
    const int b = bid >> 4;                // 2*NCHUNK = 16
    const int f = fh * 256 + threadIdx.x;  // coalesced feature index
    const int t0 = chunk * CL;

    const size_t base = ((size_t)b * Tc + t0) * Fc + f;
    const float* xp = x + base;

    float s_m, s_v;
    if (chunk == 0) {
        // exact initial state: state[0,b,f] (mean), state[1,b,f] (mean-square)
        s_m = state[b * Fc + f];
        s_v = state[Bc * Fc + b * Fc + f];
    } else {
        // halo warmup; truncated history contributes <= 0.9^KH ~ 1.4e-6
        s_m = 0.f;
        s_v = 0.f;
        const float* wp = xp - (size_t)KH * Fc;
#pragma unroll 16
        for (int i = 0; i < KH; ++i) {
            float xv = wp[(size_t)i * Fc];
            float px = ALPHA * xv;
            s_m = fmaf(OMA, s_m, px);
            s_v = fmaf(OMA, s_v, px * xv);
        }
    }

    float* op = out + base;
#pragma unroll 16
    for (int i = 0; i < CL; ++i) {
        float xv = xp[(size_t)i * Fc];
        float px = ALPHA * xv;
        s_m = fmaf(OMA, s_m, px);
        s_v = fmaf(OMA, s_v, px * xv);
        float var = fmaf(-s_m, s_m, s_v);          // v - m^2
        float r = (xv - s_m) * rsqrtf(var + EPS);
        __builtin_nontemporal_store(r, &op[(size_t)i * Fc]);  // write-once stream
    }

    if (chunk == NCHUNK - 1) {
        // final_state [2,B,F] appended after x_norm
        const size_t so = (size_t)Bc * Tc * Fc;
        out[so + (size_t)b * Fc + f] = s_m;
        out[so + (size_t)Bc * Fc + (size_t)b * Fc + f] = s_v;
    }
}

extern "C" void kernel_launch(void* const* d_in, const int* in_sizes, int n_in,
                              void* d_out, int out_size, void* d_ws, size_t ws_size,
                              hipStream_t stream) {
    const float* x = (const float*)d_in[0];      // [B,T,F] f32
    const float* st = (const float*)d_in[1];     // [2,B,F] f32
    float* out = (float*)d_out;                  // x_norm + final_state

    dim3 grid(Bc * NCHUNK * 2);                  // 256
    dim3 block(256);
    tn_kernel<<<grid, block, 0, stream>>>(x, st, out);
}